// Round 7
// baseline (32.382 us; speedup 1.0000x reference)
//
#include <hip/hip_runtime.h>

#define CIN  64
#define COUT 64
#define Hn   128
#define Wn   128
#define HW   (Hn * Wn)
#define KDIM 576
#define WROW 1152   // fallback Wtb row stride in bytes
#define EROW 640    // fallback emap row stride in bytes

// r7 blocking: 4 rows x 8 cols per block -> 8 x 12 staged window
#define NRQ 8        // staged rows
#define NCQ 12       // staged cols
#define NCHUNKQ (NRQ * NCQ * 8)   // 16B chunks = 768 = 3*256 exactly
#define PIXB 144     // padded pixel stride (9x16B; bank rotation, no XOR) [r6-validated]
#define TILE_BYTES (NRQ * NCQ * PIXB)  // 13824

typedef __attribute__((ext_vector_type(8))) short bf16x8;
typedef __attribute__((ext_vector_type(4))) float f32x4;
typedef __attribute__((ext_vector_type(2))) float f32x2;

__device__ __forceinline__ unsigned short f2bf(float f) {
    unsigned u = __float_as_uint(f);
    unsigned r = u + 0x7FFFu + ((u >> 16) & 1u);   // RNE
    return (unsigned short)(r >> 16);
}
// hardware packed f32->bf16 (RNE), 1 VALU op (r6-validated: == f2bf bit-for-bit).
__device__ __forceinline__ unsigned pk2c(float a, float b) {
    unsigned r;
    asm("v_cvt_pk_bf16_f32 %0, %1, %2" : "=v"(r) : "v"(a), "v"(b));
    return r;
}

// ============================ FAST PATH =====================================

// Fused prep (r1/r3/r6-validated): blocks [0,1024) transpose x; [1024,1168) Wtb2.
__global__ __launch_bounds__(256) void prep_fused(
    const float* __restrict__ x, const float* __restrict__ weight,
    unsigned short* __restrict__ xt, unsigned short* __restrict__ Wtb2)
{
    __shared__ float fbuf[64][65];
    if (blockIdx.x >= 1024) {
        int e = (blockIdx.x - 1024) * 256 + threadIdx.x;
        if (e < COUT * KDIM) {
            int o = e / KDIM, k = e % KDIM;
            int n = k >> 6, c = k & 63;
            int u = n % 3, v = n / 3;
            float w0 = weight[((o * CIN + c) * 3 + 0) * 3 + v];
            float w2 = weight[((o * CIN + c) * 3 + 2) * 3 + v];
            float val = (u == 0) ? w0 : ((u == 1) ? (-w0 - w2) : w2);
            int s = c >> 5;
            int ce = c & 31;
            Wtb2[((n * 2 + s) * 64 + o) * 32 + ce] = f2bf(val);
        }
        return;
    }
    const int blk = blockIdx.x;            // b*256 + h*2 + wtile
    const int b   = blk >> 8;
    const int rem = blk & 255;
    const int h   = rem >> 1;
    const int w0  = (rem & 1) << 6;
    const int t   = threadIdx.x;
    {
        int wq = t & 63, cq = t >> 6;
        const float* xp = x + ((size_t)(b * CIN + cq * 16) * Hn + h) * Wn + w0 + wq;
        #pragma unroll
        for (int r = 0; r < 16; ++r)
            fbuf[wq][cq * 16 + r] = xp[(size_t)r * HW];
    }
    __syncthreads();
    {
        int wq = t >> 2, q = t & 3;
        const float* row = &fbuf[wq][q * 16];
        uint4 d0, d1;
        d0.x = pk2c(row[0],  row[1]);  d0.y = pk2c(row[2],  row[3]);
        d0.z = pk2c(row[4],  row[5]);  d0.w = pk2c(row[6],  row[7]);
        d1.x = pk2c(row[8],  row[9]);  d1.y = pk2c(row[10], row[11]);
        d1.z = pk2c(row[12], row[13]); d1.w = pk2c(row[14], row[15]);
        unsigned short* op = xt + ((size_t)(b * Hn + h) * Wn + w0 + wq) * 64 + q * 16;
        *reinterpret_cast<uint4*>(op)     = d0;
        *reinterpret_cast<uint4*>(op + 8) = d1;
    }
}

// axis geometry (validated r5/r6): local tile indices + bilinear weights.
template<int D>
__device__ __forceinline__ void axis_pts(float s, int base1, int org,
                                         int& l0, int& l1, float& w0, float& w1)
{
    float p  = (float)D * s + (float)base1;
    float f  = floorf(p);
    float q0 = fminf(fmaxf(f,       0.f), 129.f);
    float q1 = fminf(fmaxf(f + 1.f, 0.f), 129.f);
    w0 = 1.f + (q0 - p);  w1 = 1.f - (q1 - p);
    int i0 = (int)q0, i1 = (int)q1;
    if (i0 < 1 || i0 > 128) w0 = 0.f;
    if (i1 < 1 || i1 > 128) w1 = 0.f;
    l0 = min(max(i0 - 1, 0), 127) - org;
    l1 = min(max(i1 - 1, 0), 127) - org;
}

// pixel (lr,lc) -> L-half byte offset in the pad-144 tile (+g16 channel slot).
// H-half is +64 (ds_read offset immediate at the consumer).
__device__ __forceinline__ unsigned pixb(int lr, int lc, int g16) {
    return (unsigned)((lr * NCQ + lc) * PIXB + g16);
}

// per-wave geometry with axis reuse (r6-validated).
template<int DXc, int DYc, int EDX, int EDY>
__device__ __forceinline__ void geoW(float s1, float s2, int ipx, int iorg,
        int jpx, int jorg, int g16, unsigned A[4], float AG[4],
        unsigned B[2], float BG[2])
{
    int r0, r1, c0, c1; float wx0, wx1, wy0, wy1;
    axis_pts<DXc>(s1, ipx + 1, iorg, r0, r1, wx0, wx1);
    axis_pts<DYc>(s2, jpx + 1, jorg, c0, c1, wy0, wy1);
    A[0] = pixb(r0, c0, g16);  AG[0] = wx0 * wy0;
    A[1] = pixb(r0, c1, g16);  AG[1] = wx0 * wy1;
    A[2] = pixb(r1, c0, g16);  AG[2] = wx1 * wy0;
    A[3] = pixb(r1, c1, g16);  AG[3] = wx1 * wy1;
    if (EDY == 0) {                    // w0, w2: reuse x-axis, fixed col
        int lc = jpx - jorg;
        B[0] = pixb(r0, lc, g16);  BG[0] = wx0;
        B[1] = pixb(r1, lc, g16);  BG[1] = wx1;
    } else if (EDY == DYc) {           // w3: reuse y-axis, fixed row
        int lr = ipx - iorg;
        B[0] = pixb(lr, c0, g16);  BG[0] = wy0;
        B[1] = pixb(lr, c1, g16);  BG[1] = wy1;
    } else {                           // w1: extra y-axis (EDY = -1)
        int e0, e1; float v0, v1;
        axis_pts<EDY>(s2, jpx + 1, jorg, e0, e1, v0, v1);
        int lr = ipx - iorg;
        B[0] = pixb(lr, e0, g16);  BG[0] = v0;
        B[1] = pixb(lr, e1, g16);  BG[1] = v1;
    }
}

// bf16 pair -> f32x2 (lo<<16, hi&FFFF0000) — same bit patterns as r6's fma16.
__device__ __forceinline__ f32x2 bfpair(unsigned u) {
    f32x2 r;
    r.x = __uint_as_float(u << 16);
    r.y = __uint_as_float(u & 0xFFFF0000u);
    return r;
}

// packed-f32 interp fma: identical per-element fma chain (r5/r6-validated).
__device__ __forceinline__ void fma16p(uint4 rl, uint4 rh, float gw,
                                       f32x2* v0, f32x2* v1) {
    const unsigned* u0 = reinterpret_cast<const unsigned*>(&rl);
    const unsigned* u1 = reinterpret_cast<const unsigned*>(&rh);
    f32x2 g2; g2.x = gw; g2.y = gw;
    #pragma unroll
    for (int q = 0; q < 4; ++q) {
        v0[q] = __builtin_elementwise_fma(g2, bfpair(u0[q]), v0[q]);
        v1[q] = __builtin_elementwise_fma(g2, bfpair(u1[q]), v1[q]);
    }
}

__device__ __forceinline__ bf16x8 packv2(const f32x2* v) {
    uint4 p;
    p.x = pk2c(v[0].x, v[0].y); p.y = pk2c(v[1].x, v[1].y);
    p.z = pk2c(v[2].x, v[2].y); p.w = pk2c(v[3].x, v[3].y);
    union { uint4 u; bf16x8 b; } cv; cv.u = p;
    return cv.b;
}

// r6 structure (validated: 31.9us).  r7 changes:
//  (a) 4x8 blocking: window 8x12=96 px (was 6x20=120), staging 3 exact iters
//      (was 4 w/ predication), tile 13.8KB.  Pixel-group = 2 rows x 8 cols;
//      per-pixel fp math unchanged -> bit-identical output.
//  (b) XCD-aware block swizzle (bijective, 2048%8==0): consecutive spatial
//      tiles share an XCD L2 -> window re-fetch overlap becomes L2-local.
__global__ __launch_bounds__(256, 3) void ddconv_ws3(
    const unsigned short* __restrict__ xt, const float* __restrict__ alpha,
    const unsigned short* __restrict__ Wtb2, const float* __restrict__ bias,
    float* __restrict__ out)
{
    __shared__ __align__(16) char smem[40960];   // tile 13824 + sincos 256; reduce reuses 40960

    // XCD swizzle: 2048 blocks, 8 XCDs -> chunk of 256 contiguous per XCD
    const int blk  = ((blockIdx.x & 7) << 8) + (blockIdx.x >> 3);
    const int b    = blk >> 9;             // blk = b*512 + (i0/4)*16 + (j0/8)
    const int rem  = blk & 511;
    const int i0   = (rem >> 4) << 2;
    const int j0   = (rem & 15) << 3;
    const int t    = threadIdx.x;
    const int lane = t & 63;
    const int w    = t >> 6;
    const int llo  = lane & 15;
    const int g    = lane >> 4;
    const int g16  = g * 16;
    const int iorg = i0 - 2, jorg = j0 - 2;

    const char* xtb = (const char*)xt + (size_t)b * HW * 128;
    const char* wt2 = (const char*)Wtb2;
    const int arow  = llo * 64 + g16;

    // ---- stage 8 x 12 window of xt, pad-144, load/write split (r3/r5/r6) ----
    char* tile = smem;
    uint4    sv[3];
    unsigned sla[3];
    {
        const char* sgp[3];
        const int slot16 = (t & 7) << 4;           // slot const across k (256%8==0)
        #pragma unroll
        for (int k = 0; k < 3; ++k) {
            int q  = t + k * 256;
            int rc = q >> 3;                       // 0..95
            int row = rc / NCQ;
            int col = rc - row * NCQ;
            int ru  = min(max(iorg + row, 0), 127);
            int cu  = min(max(jorg + col, 0), 127);
            sgp[k] = xtb + (size_t)(((ru << 7) + cu) << 7) + slot16;
            sla[k] = (unsigned)(rc * PIXB) + slot16;
        }
        #pragma unroll
        for (int k = 0; k < 3; ++k)
            sv[k] = *reinterpret_cast<const uint4*>(sgp[k]);
    }
    #pragma unroll
    for (int k = 0; k < 3; ++k)
        *reinterpret_cast<uint4*>(tile + sla[k]) = sv[k];

    // ---- per-wave A-fragment preload (validated r6; after staging loads) ----
    const int nn0 = (w==0)?0:(w==1)?2:(w==2)?6:8;
    const int nn1 = (w==0)?1:(w==1)?3:(w==2)?7:5;
    const int cs  = w >> 1;
    bf16x8 Ata[2][4], Atb[2][4], Ac0, Ac1;
    #pragma unroll
    for (int s = 0; s < 2; ++s)
      #pragma unroll
      for (int ot = 0; ot < 4; ++ot) {
        Ata[s][ot] = *reinterpret_cast<const bf16x8*>(wt2 + (nn0*2+s)*4096 + ot*1024 + arow);
        Atb[s][ot] = *reinterpret_cast<const bf16x8*>(wt2 + (nn1*2+s)*4096 + ot*1024 + arow);
      }
    Ac0 = *reinterpret_cast<const bf16x8*>(wt2 + (8+cs)*4096 + ((w&1)*2  )*1024 + arow);
    Ac1 = *reinterpret_cast<const bf16x8*>(wt2 + (8+cs)*4096 + ((w&1)*2+1)*1024 + arow);

    // ---- rotation: sincosf once per pixel on wave 0, broadcast via LDS ----
    // pixel t (t<32): row i0 + (t>>3), col j0 + (t&7).
    // consumer pixel (pg,llo): row i0 + pg*2 + (llo>>3), col j0 + (llo&7)
    //   -> its t index = pg*16 + llo.
    float* sAB = reinterpret_cast<float*>(smem + TILE_BYTES);  // 64 floats
    if (t < 32) {
        float a = alpha[(b * Hn + i0 + (t >> 3)) * Wn + j0 + (t & 7)];
        float sa, ca;
        sincosf(a, &sa, &ca);
        sAB[t]      = ca + sa;   // S1
        sAB[32 + t] = ca - sa;   // S2
    }

    f32x4 acc[2][4];
    #pragma unroll
    for (int pg = 0; pg < 2; ++pg)
      #pragma unroll
      for (int ot = 0; ot < 4; ++ot) acc[pg][ot] = (f32x4){0.f, 0.f, 0.f, 0.f};

    __syncthreads();

    float S1[2], S2[2];
    #pragma unroll
    for (int pg = 0; pg < 2; ++pg) {
        S1[pg] = sAB[pg * 16 + llo];
        S2[pg] = sAB[32 + pg * 16 + llo];
    }

    #define LDT(o) (*reinterpret_cast<const uint4*>(tile + (o)))

    #pragma unroll
    for (int pg = 0; pg < 2; ++pg) {
        const int ipx = i0 + pg * 2 + (llo >> 3);
        const int jpx = j0 + (llo & 7);

        // -- geometry: L-half addresses + weights (H = +64 immediate) --
        unsigned A[4], B[2];
        float    AG[4], BG[2];
        if (w == 0) {
            geoW<-1,-1,-1, 0>(S1[pg], S2[pg], ipx, iorg, jpx, jorg, g16, A, AG, B, BG);
        } else if (w == 1) {
            geoW<-1, 1, 0,-1>(S1[pg], S2[pg], ipx, iorg, jpx, jorg, g16, A, AG, B, BG);
        } else if (w == 2) {
            geoW< 1,-1, 1, 0>(S1[pg], S2[pg], ipx, iorg, jpx, jorg, g16, A, AG, B, BG);
        } else {
            geoW< 1, 1, 0, 1>(S1[pg], S2[pg], ipx, iorg, jpx, jorg, g16, A, AG, B, BG);
        }
        unsigned cAddr = pixb(ipx - iorg, jpx - jorg, g16) + (cs ? 64u : 0u);

        // -- hoisted load burst: 13 ds_read_b128 (H-halves via offset:64) --
        uint4 La[4], Ha[4];
        #pragma unroll
        for (int p = 0; p < 4; ++p) {
            La[p] = LDT(A[p]);
            Ha[p] = LDT(A[p] + 64);
        }
        uint4 Lb[2], Hb[2];
        #pragma unroll
        for (int p = 0; p < 2; ++p) {
            Lb[p] = LDT(B[p]);
            Hb[p] = LDT(B[p] + 64);
        }
        bf16x8 bc;
        {
            union { uint4 u; bf16x8 b; } cv; cv.u = LDT(cAddr); bc = cv.b;
        }

        // -- consume (same fp element order as r5/r6, packed 2-wide) --
        f32x2 v0[4], v1[4];
        #pragma unroll
        for (int q = 0; q < 4; ++q) { v0[q] = (f32x2){0.f,0.f}; v1[q] = (f32x2){0.f,0.f}; }
        #pragma unroll
        for (int p = 0; p < 4; ++p) fma16p(La[p], Ha[p], AG[p], v0, v1);
        bf16x8 bA0 = packv2(v0), bA1 = packv2(v1);

        f32x2 u0[4], u1[4];
        #pragma unroll
        for (int q = 0; q < 4; ++q) { u0[q] = (f32x2){0.f,0.f}; u1[q] = (f32x2){0.f,0.f}; }
        #pragma unroll
        for (int p = 0; p < 2; ++p) fma16p(Lb[p], Hb[p], BG[p], u0, u1);
        bf16x8 bB0 = packv2(u0), bB1 = packv2(u1);

        #pragma unroll
        for (int ot = 0; ot < 4; ++ot) {
            acc[pg][ot] = __builtin_amdgcn_mfma_f32_16x16x32_bf16(Ata[0][ot], bA0, acc[pg][ot], 0, 0, 0);
            acc[pg][ot] = __builtin_amdgcn_mfma_f32_16x16x32_bf16(Ata[1][ot], bA1, acc[pg][ot], 0, 0, 0);
            acc[pg][ot] = __builtin_amdgcn_mfma_f32_16x16x32_bf16(Atb[0][ot], bB0, acc[pg][ot], 0, 0, 0);
            acc[pg][ot] = __builtin_amdgcn_mfma_f32_16x16x32_bf16(Atb[1][ot], bB1, acc[pg][ot], 0, 0, 0);
        }
        if (w & 1) {
            acc[pg][2] = __builtin_amdgcn_mfma_f32_16x16x32_bf16(Ac0, bc, acc[pg][2], 0, 0, 0);
            acc[pg][3] = __builtin_amdgcn_mfma_f32_16x16x32_bf16(Ac1, bc, acc[pg][3], 0, 0, 0);
        } else {
            acc[pg][0] = __builtin_amdgcn_mfma_f32_16x16x32_bf16(Ac0, bc, acc[pg][0], 0, 0, 0);
            acc[pg][1] = __builtin_amdgcn_mfma_f32_16x16x32_bf16(Ac1, bc, acc[pg][1], 0, 0, 0);
        }
    }
    #undef LDT

    // ---- cross-wave K-reduce through LDS (validated r4/r6) ----
    __syncthreads();
    #pragma unroll
    for (int pg = 0; pg < 2; ++pg)
      #pragma unroll
      for (int ot = 0; ot < 4; ++ot)
        *reinterpret_cast<f32x4*>(smem + ((pg*256 + w*64 + lane)*80) + ot*16) = acc[pg][ot];
    __syncthreads();
    {
        const int eq = w;
        #pragma unroll
        for (int pg = 0; pg < 2; ++pg) {
            f32x4 s = (f32x4){0.f, 0.f, 0.f, 0.f};
            #pragma unroll
            for (int ww = 0; ww < 4; ++ww)
                s += *reinterpret_cast<const f32x4*>(smem + ((pg*256 + ww*64 + lane)*80) + eq*16);
            float* ob = out + (size_t)b * COUT * HW
                      + (size_t)(i0 + pg * 2 + (llo >> 3)) * Wn + j0 + (llo & 7);
            #pragma unroll
            for (int r = 0; r < 4; ++r) {
                int o = eq * 16 + g * 4 + r;
                ob[(size_t)o * HW] = s[r] + bias[o];
            }
        }
    }
}

// ====================== FALLBACK PATH (round-2, validated) ==================

__device__ __forceinline__ unsigned pk2f(float a, float b) {
    return (unsigned)f2bf(a) | ((unsigned)f2bf(b) << 16);
}

__global__ void prep_weights(const float* __restrict__ weight,
                             unsigned short* __restrict__ Wtb) {
    int e = blockIdx.x * 256 + threadIdx.x;
    if (e >= COUT * KDIM) return;
    int o = e / KDIM, k = e % KDIM;
    int n = k >> 6, c = k & 63;
    int u = n % 3, v = n / 3;
    float w0 = weight[((o * CIN + c) * 3 + 0) * 3 + v];
    float w2 = weight[((o * CIN + c) * 3 + 2) * 3 + v];
    float val = (u == 0) ? w0 : ((u == 1) ? (-w0 - w2) : w2);
    Wtb[o * KDIM + k] = f2bf(val);
}

template<int DX, int DY>
__device__ __forceinline__ void gatherG(const float* __restrict__ xb,
    float s1, float s2, int i, int jj, int klocal,
    char* myrow, unsigned swz, int c0s, int c1s)
{
    int ix0 = 0, ix1 = 0; float wx0 = 1.f, wx1 = 0.f;
    if (DX != 0) {
        float px = (float)DX * s1 + (float)(i + 1);
        float fx = floorf(px);
        float qx0 = fminf(fmaxf(fx, 0.f), 129.f);
        float qx1 = fminf(fmaxf(fx + 1.f, 0.f), 129.f);
        wx0 = 1.f + (qx0 - px); wx1 = 1.f - (qx1 - px);
        ix0 = (int)qx0; ix1 = (int)qx1;
    } else { ix0 = i + 1; }
    int iy0 = 0, iy1 = 0; float wy0 = 1.f, wy1 = 0.f;
    if (DY != 0) {
        float py = (float)DY * s2 + (float)(jj + 1);
        float fy = floorf(py);
        float qy0 = fminf(fmaxf(fy, 0.f), 129.f);
        float qy1 = fminf(fmaxf(fy + 1.f, 0.f), 129.f);
        wy0 = 1.f + (qy0 - py); wy1 = 1.f - (qy1 - py);
        iy0 = (int)qy0; iy1 = (int)qy1;
    } else { iy0 = jj + 1; }

    constexpr int NX = (DX ? 2 : 1), NY = (DY ? 2 : 1), NT = NX * NY;
    unsigned idx[NT]; float g[NT];
    const int   ixs[2] = { ix0, ix1 };  const float wxs[2] = { wx0, wx1 };
    const int   iys[2] = { iy0, iy1 };  const float wys[2] = { wy0, wy1 };
    #pragma unroll
    for (int xi = 0; xi < NX; ++xi)
      #pragma unroll
      for (int yi = 0; yi < NY; ++yi) {
        int ix = ixs[xi], iy = iys[yi];
        bool ok = (ix >= 1) && (ix <= Hn) && (iy >= 1) && (iy <= Wn);
        int cx = min(max(ix, 1), Hn) - 1;
        int cy = min(max(iy, 1), Wn) - 1;
        idx[xi * NY + yi] = (unsigned)(cx * Wn + cy);
        g[xi * NY + yi]   = ok ? wxs[xi] * wys[yi] : 0.f;
      }
    for (int c0 = c0s; c0 < c1s; c0 += 8) {
        float v[8];
        #pragma unroll
        for (int cc = 0; cc < 8; ++cc) {
            unsigned coff = (unsigned)(c0 + cc) * HW;
            float acc2 = 0.f;
            #pragma unroll
            for (int tp = 0; tp < NT; ++tp)
                acc2 = fmaf(g[tp], xb[coff + idx[tp]], acc2);
            v[cc] = acc2;
        }
        uint4 d;
        d.x = pk2f(v[0], v[1]); d.y = pk2f(v[2], v[3]);
        d.z = pk2f(v[4], v[5]); d.w = pk2f(v[6], v[7]);
        unsigned addr = (unsigned)(klocal + c0) * 2u;
        *reinterpret_cast<uint4*>(myrow + (addr ^ swz)) = d;
    }
}

template<int KS>
__device__ __forceinline__ void mfma_phase(const char* emap,
    const unsigned short* __restrict__ Wtb,
    int w, int lane, int passbyte, f32x4 acc[4])
{
    const int llo = lane & 15, lhi = lane >> 4;
    const unsigned prow = (unsigned)(w * 16 + llo);
    const unsigned psw  = (prow & 7u) << 4;
    const char* erow = emap + prow * EROW;
    const char* wtb  = (const char*)Wtb + passbyte + lhi * 16;
    #pragma unroll
    for (int s = 0; s < KS; ++s) {
        unsigned kb = (unsigned)(s * 64 + lhi * 16);
        bf16x8 bf = *reinterpret_cast<const bf16x8*>(erow + (kb ^ psw));
        #pragma unroll
        for (int ot = 0; ot < 4; ++ot) {
            const char* ap = wtb + (ot * 16 + llo) * WROW + s * 64;
            bf16x8 af = *reinterpret_cast<const bf16x8*>(ap);
            acc[ot] = __builtin_amdgcn_mfma_f32_16x16x32_bf16(af, bf, acc[ot], 0, 0, 0);
        }
    }
}

__global__ __launch_bounds__(256, 3) void ddconv_mfma(
    const float* __restrict__ x, const float* __restrict__ alpha,
    const unsigned short* __restrict__ Wtb, const float* __restrict__ bias,
    float* __restrict__ out)
{
    __shared__ __align__(16) char emap[64 * EROW];
    const int blk  = blockIdx.x;
    const int b    = blk >> 8;
    const int rem  = blk & 255;
    const int i    = rem >> 1;
    const int j0   = (rem & 1) << 6;
    const int t    = threadIdx.x;
    const int lane = t & 63;
    const int w    = t >> 6;
    const int jj   = j0 + lane;
    const float* xb = x + (size_t)b * CIN * HW;
    float a = alpha[(b * Hn + i) * Wn + jj];
    float sa, ca;
    sincosf(a, &sa, &ca);
    const float s1 = ca + sa, s2 = ca - sa;
    char* myrow = emap + lane * EROW;
    const unsigned swz = (unsigned)((lane & 7) << 4);
    f32x4 acc[4];
    #pragma unroll
    for (int ot = 0; ot < 4; ++ot) acc[ot] = (f32x4){0.f, 0.f, 0.f, 0.f};
    if (w == 0)      { gatherG<-1,-1>(xb, s1, s2, i, jj,   0, myrow, swz,  0, 48); }
    else if (w == 1) { gatherG<-1,-1>(xb, s1, s2, i, jj,   0, myrow, swz, 48, 64);
                       gatherG<-1, 0>(xb, s1, s2, i, jj,  64, myrow, swz,  0, 64); }
    else if (w == 2) { gatherG<-1, 1>(xb, s1, s2, i, jj, 128, myrow, swz,  0, 48); }
    else             { gatherG<-1, 1>(xb, s1, s2, i, jj, 128, myrow, swz, 48, 64);
                       gatherG< 0,-1>(xb, s1, s2, i, jj, 192, myrow, swz,  0, 64); }
    __syncthreads();
    mfma_phase<8>(emap, Wtb, w, lane, 0, acc);
    __syncthreads();
    if (w == 0)      { gatherG< 1,-1>(xb, s1, s2, i, jj, 128, myrow, swz,  0, 56); }
    else if (w == 1) { gatherG< 1,-1>(xb, s1, s2, i, jj, 128, myrow, swz, 56, 64);
                       gatherG< 1, 1>(xb, s1, s2, i, jj, 256, myrow, swz,  0, 48); }
    else if (w == 2) { gatherG< 1, 1>(xb, s1, s2, i, jj, 256, myrow, swz, 48, 64);
                       gatherG< 0, 1>(xb, s1, s2, i, jj,  64, myrow, swz,  0, 64); }
    else             { gatherG< 1, 0>(xb, s1, s2, i, jj, 192, myrow, swz,  0, 64);
                       gatherG< 0, 0>(xb, s1, s2, i, jj,   0, myrow, swz,  0, 64); }
    __syncthreads();
    mfma_phase<10>(emap, Wtb, w, lane, 512, acc);
    const int llo = lane & 15, lhi = lane >> 4;
    float* ob = out + (size_t)b * COUT * HW + (size_t)i * Wn + j0 + w * 16 + llo;
    #pragma unroll
    for (int ot = 0; ot < 4; ++ot)
      #pragma unroll
      for (int r = 0; r < 4; ++r) {
        int o = ot * 16 + lhi * 4 + r;
        ob[(size_t)o * HW] = acc[ot][r] + bias[o];
      }
}

// ============================================================================

extern "C" void kernel_launch(void* const* d_in, const int* in_sizes, int n_in,
                              void* d_out, int out_size, void* d_ws, size_t ws_size,
                              hipStream_t stream) {
    const float* x      = (const float*)d_in[0];
    const float* alpha  = (const float*)d_in[1];
    const float* weight = (const float*)d_in[2];
    const float* bias   = (const float*)d_in[3];
    float* out = (float*)d_out;

    const size_t WT_BYTES = (size_t)COUT * KDIM * 2;          // 73728
    const size_t XT_BYTES = (size_t)4 * HW * CIN * 2;         // 8388608

    if (ws_size >= WT_BYTES + XT_BYTES) {
        unsigned short* Wtb2 = (unsigned short*)d_ws;
        unsigned short* xt   = (unsigned short*)((char*)d_ws + WT_BYTES);
        prep_fused<<<1168, 256, 0, stream>>>(x, weight, xt, Wtb2);
        ddconv_ws3<<<4 * (Hn / 4) * (Wn / 8), 256, 0, stream>>>(xt, alpha, Wtb2, bias, out);
    } else {
        unsigned short* Wtb = (unsigned short*)d_ws;          // round-2 layout
        prep_weights<<<(COUT * KDIM + 255) / 256, 256, 0, stream>>>(weight, Wtb);
        ddconv_mfma<<<4 * Hn * (Wn / 64), 256, 0, stream>>>(x, alpha, Wtb, bias, out);
    }
}

// Round 8
// 31.908 us; speedup vs baseline: 1.0149x; 1.0149x over previous
//
#include <hip/hip_runtime.h>

#define CIN  64
#define COUT 64
#define Hn   128
#define Wn   128
#define HW   (Hn * Wn)
#define KDIM 576
#define WROW 1152   // fallback Wtb row stride in bytes
#define EROW 640    // fallback emap row stride in bytes

// r8 blocking: 4 rows x 16 cols per block (two 4x8 sub-tiles) -> 8 x 20 window
#define NRQ 8        // staged rows
#define NCQ 20       // staged cols
#define NCHUNKQ (NRQ * NCQ * 8)   // 16B chunks = 1280 = 5*256 exactly
#define PIXB 144     // padded pixel stride (9x16B; bank rotation, no XOR) [r6-validated]
#define TILE_BYTES (NRQ * NCQ * PIXB)  // 23040
#define SAB_OFF  TILE_BYTES            // 23040: 128 floats (512B)
#define RED_OFF  (TILE_BYTES + 512)    // 23552: reduce buffer 256*80 = 20480
#define SMEM_BYTES (RED_OFF + 20480)   // 44032 -> 3 blocks/CU by LDS

typedef __attribute__((ext_vector_type(8))) short bf16x8;
typedef __attribute__((ext_vector_type(4))) float f32x4;
typedef __attribute__((ext_vector_type(2))) float f32x2;

__device__ __forceinline__ unsigned short f2bf(float f) {
    unsigned u = __float_as_uint(f);
    unsigned r = u + 0x7FFFu + ((u >> 16) & 1u);   // RNE
    return (unsigned short)(r >> 16);
}
// hardware packed f32->bf16 (RNE), 1 VALU op (r6-validated: == f2bf bit-for-bit).
__device__ __forceinline__ unsigned pk2c(float a, float b) {
    unsigned r;
    asm("v_cvt_pk_bf16_f32 %0, %1, %2" : "=v"(r) : "v"(a), "v"(b));
    return r;
}

// ============================ FAST PATH =====================================

// Fused prep (r1/r3/r6-validated): blocks [0,1024) transpose x; [1024,1168) Wtb2.
__global__ __launch_bounds__(256) void prep_fused(
    const float* __restrict__ x, const float* __restrict__ weight,
    unsigned short* __restrict__ xt, unsigned short* __restrict__ Wtb2)
{
    __shared__ float fbuf[64][65];
    if (blockIdx.x >= 1024) {
        int e = (blockIdx.x - 1024) * 256 + threadIdx.x;
        if (e < COUT * KDIM) {
            int o = e / KDIM, k = e % KDIM;
            int n = k >> 6, c = k & 63;
            int u = n % 3, v = n / 3;
            float w0 = weight[((o * CIN + c) * 3 + 0) * 3 + v];
            float w2 = weight[((o * CIN + c) * 3 + 2) * 3 + v];
            float val = (u == 0) ? w0 : ((u == 1) ? (-w0 - w2) : w2);
            int s = c >> 5;
            int ce = c & 31;
            Wtb2[((n * 2 + s) * 64 + o) * 32 + ce] = f2bf(val);
        }
        return;
    }
    const int blk = blockIdx.x;            // b*256 + h*2 + wtile
    const int b   = blk >> 8;
    const int rem = blk & 255;
    const int h   = rem >> 1;
    const int w0  = (rem & 1) << 6;
    const int t   = threadIdx.x;
    {
        int wq = t & 63, cq = t >> 6;
        const float* xp = x + ((size_t)(b * CIN + cq * 16) * Hn + h) * Wn + w0 + wq;
        #pragma unroll
        for (int r = 0; r < 16; ++r)
            fbuf[wq][cq * 16 + r] = xp[(size_t)r * HW];
    }
    __syncthreads();
    {
        int wq = t >> 2, q = t & 3;
        const float* row = &fbuf[wq][q * 16];
        uint4 d0, d1;
        d0.x = pk2c(row[0],  row[1]);  d0.y = pk2c(row[2],  row[3]);
        d0.z = pk2c(row[4],  row[5]);  d0.w = pk2c(row[6],  row[7]);
        d1.x = pk2c(row[8],  row[9]);  d1.y = pk2c(row[10], row[11]);
        d1.z = pk2c(row[12], row[13]); d1.w = pk2c(row[14], row[15]);
        unsigned short* op = xt + ((size_t)(b * Hn + h) * Wn + w0 + wq) * 64 + q * 16;
        *reinterpret_cast<uint4*>(op)     = d0;
        *reinterpret_cast<uint4*>(op + 8) = d1;
    }
}

// axis geometry (validated r5/r6): local tile indices + bilinear weights.
template<int D>
__device__ __forceinline__ void axis_pts(float s, int base1, int org,
                                         int& l0, int& l1, float& w0, float& w1)
{
    float p  = (float)D * s + (float)base1;
    float f  = floorf(p);
    float q0 = fminf(fmaxf(f,       0.f), 129.f);
    float q1 = fminf(fmaxf(f + 1.f, 0.f), 129.f);
    w0 = 1.f + (q0 - p);  w1 = 1.f - (q1 - p);
    int i0 = (int)q0, i1 = (int)q1;
    if (i0 < 1 || i0 > 128) w0 = 0.f;
    if (i1 < 1 || i1 > 128) w1 = 0.f;
    l0 = min(max(i0 - 1, 0), 127) - org;
    l1 = min(max(i1 - 1, 0), 127) - org;
}

// pixel (lr,lc) -> L-half byte offset in the pad-144 tile (+g16 channel slot).
// H-half is +64 (ds_read offset immediate at the consumer).
__device__ __forceinline__ unsigned pixb(int lr, int lc, int g16) {
    return (unsigned)((lr * NCQ + lc) * PIXB + g16);
}

// per-wave geometry with axis reuse (r6-validated).
template<int DXc, int DYc, int EDX, int EDY>
__device__ __forceinline__ void geoW(float s1, float s2, int ipx, int iorg,
        int jpx, int jorg, int g16, unsigned A[4], float AG[4],
        unsigned B[2], float BG[2])
{
    int r0, r1, c0, c1; float wx0, wx1, wy0, wy1;
    axis_pts<DXc>(s1, ipx + 1, iorg, r0, r1, wx0, wx1);
    axis_pts<DYc>(s2, jpx + 1, jorg, c0, c1, wy0, wy1);
    A[0] = pixb(r0, c0, g16);  AG[0] = wx0 * wy0;
    A[1] = pixb(r0, c1, g16);  AG[1] = wx0 * wy1;
    A[2] = pixb(r1, c0, g16);  AG[2] = wx1 * wy0;
    A[3] = pixb(r1, c1, g16);  AG[3] = wx1 * wy1;
    if (EDY == 0) {                    // w0, w2: reuse x-axis, fixed col
        int lc = jpx - jorg;
        B[0] = pixb(r0, lc, g16);  BG[0] = wx0;
        B[1] = pixb(r1, lc, g16);  BG[1] = wx1;
    } else if (EDY == DYc) {           // w3: reuse y-axis, fixed row
        int lr = ipx - iorg;
        B[0] = pixb(lr, c0, g16);  BG[0] = wy0;
        B[1] = pixb(lr, c1, g16);  BG[1] = wy1;
    } else {                           // w1: extra y-axis (EDY = -1)
        int e0, e1; float v0, v1;
        axis_pts<EDY>(s2, jpx + 1, jorg, e0, e1, v0, v1);
        int lr = ipx - iorg;
        B[0] = pixb(lr, e0, g16);  BG[0] = v0;
        B[1] = pixb(lr, e1, g16);  BG[1] = v1;
    }
}

// bf16 pair -> f32x2 (lo<<16, hi&FFFF0000) — same bit patterns as r6's fma16.
__device__ __forceinline__ f32x2 bfpair(unsigned u) {
    f32x2 r;
    r.x = __uint_as_float(u << 16);
    r.y = __uint_as_float(u & 0xFFFF0000u);
    return r;
}

// packed-f32 interp fma: identical per-element fma chain (r5/r6-validated).
__device__ __forceinline__ void fma16p(uint4 rl, uint4 rh, float gw,
                                       f32x2* v0, f32x2* v1) {
    const unsigned* u0 = reinterpret_cast<const unsigned*>(&rl);
    const unsigned* u1 = reinterpret_cast<const unsigned*>(&rh);
    f32x2 g2; g2.x = gw; g2.y = gw;
    #pragma unroll
    for (int q = 0; q < 4; ++q) {
        v0[q] = __builtin_elementwise_fma(g2, bfpair(u0[q]), v0[q]);
        v1[q] = __builtin_elementwise_fma(g2, bfpair(u1[q]), v1[q]);
    }
}

__device__ __forceinline__ bf16x8 packv2(const f32x2* v) {
    uint4 p;
    p.x = pk2c(v[0].x, v[0].y); p.y = pk2c(v[1].x, v[1].y);
    p.z = pk2c(v[2].x, v[2].y); p.w = pk2c(v[3].x, v[3].y);
    union { uint4 u; bf16x8 b; } cv; cv.u = p;
    return cv.b;
}

// r7 structure minus XCD swizzle (L3-fit -> swizzle costs ~2%, guide m160).
// r8 change: 2 j-adjacent 4x8 sub-tiles per block (64 px), staged window
// union 8x20, A-fragments preloaded ONCE and reused for both sub-tiles
// (weight L2 traffic halved: 150->75MB), per-block overheads amortized 2x.
// Reduce runs per-(st,pg) in a 20KB side buffer (tile stays live for st=1).
// All per-pixel fp chains and reduce-sum order unchanged -> bit-identical.
__global__ __launch_bounds__(256, 3) void ddconv_ws3(
    const unsigned short* __restrict__ xt, const float* __restrict__ alpha,
    const unsigned short* __restrict__ Wtb2, const float* __restrict__ bias,
    float* __restrict__ out)
{
    __shared__ __align__(16) char smem[SMEM_BYTES];

    const int blk  = blockIdx.x;           // b*256 + (i0/4)*8 + (j0/16)
    const int b    = blk >> 8;
    const int rem  = blk & 255;
    const int i0   = (rem >> 3) << 2;
    const int j0   = (rem & 7) << 4;
    const int t    = threadIdx.x;
    const int lane = t & 63;
    const int w    = t >> 6;
    const int llo  = lane & 15;
    const int g    = lane >> 4;
    const int g16  = g * 16;
    const int iorg = i0 - 2, jorg = j0 - 2;

    const char* xtb = (const char*)xt + (size_t)b * HW * 128;
    const char* wt2 = (const char*)Wtb2;
    const int arow  = llo * 64 + g16;

    // ---- stage 8 x 20 window of xt, pad-144, load/write split (r3/r5/r6) ----
    char* tile = smem;
    uint4    sv[5];
    unsigned sla[5];
    {
        const char* sgp[5];
        const int slot16 = (t & 7) << 4;           // slot const across k (256%8==0)
        #pragma unroll
        for (int k = 0; k < 5; ++k) {
            int q  = t + k * 256;
            int rc = q >> 3;                       // 0..159
            int row = rc / NCQ;
            int col = rc - row * NCQ;
            int ru  = min(max(iorg + row, 0), 127);
            int cu  = min(max(jorg + col, 0), 127);
            sgp[k] = xtb + (size_t)(((ru << 7) + cu) << 7) + slot16;
            sla[k] = (unsigned)(rc * PIXB) + slot16;
        }
        #pragma unroll
        for (int k = 0; k < 5; ++k)
            sv[k] = *reinterpret_cast<const uint4*>(sgp[k]);
    }
    #pragma unroll
    for (int k = 0; k < 5; ++k)
        *reinterpret_cast<uint4*>(tile + sla[k]) = sv[k];

    // ---- per-wave A-fragment preload (once, reused by both sub-tiles) ----
    const int nn0 = (w==0)?0:(w==1)?2:(w==2)?6:8;
    const int nn1 = (w==0)?1:(w==1)?3:(w==2)?7:5;
    const int cs  = w >> 1;
    bf16x8 Ata[2][4], Atb[2][4], Ac0, Ac1;
    #pragma unroll
    for (int s = 0; s < 2; ++s)
      #pragma unroll
      for (int ot = 0; ot < 4; ++ot) {
        Ata[s][ot] = *reinterpret_cast<const bf16x8*>(wt2 + (nn0*2+s)*4096 + ot*1024 + arow);
        Atb[s][ot] = *reinterpret_cast<const bf16x8*>(wt2 + (nn1*2+s)*4096 + ot*1024 + arow);
      }
    Ac0 = *reinterpret_cast<const bf16x8*>(wt2 + (8+cs)*4096 + ((w&1)*2  )*1024 + arow);
    Ac1 = *reinterpret_cast<const bf16x8*>(wt2 + (8+cs)*4096 + ((w&1)*2+1)*1024 + arow);

    // ---- rotation: sincosf once per pixel (64 px) on waves 0, broadcast ----
    // pixel t (t<64): row = i0 + ((t>>4)&1)*2 + ((t>>3)&1), col = j0 + (t>>5)*8 + (t&7)
    // consumer (st,pg,llo) reads index st*32 + pg*16 + llo.
    float* sAB = reinterpret_cast<float*>(smem + SAB_OFF);  // 128 floats
    if (t < 64) {
        int row = i0 + ((t >> 4) & 1) * 2 + ((t >> 3) & 1);
        int col = j0 + (t >> 5) * 8 + (t & 7);
        float a = alpha[(b * Hn + row) * Wn + col];
        float sa, ca;
        sincosf(a, &sa, &ca);
        sAB[t]      = ca + sa;   // S1
        sAB[64 + t] = ca - sa;   // S2
    }

    __syncthreads();

    float S1[2][2], S2[2][2];
    #pragma unroll
    for (int st = 0; st < 2; ++st)
      #pragma unroll
      for (int pg = 0; pg < 2; ++pg) {
        S1[st][pg] = sAB[st * 32 + pg * 16 + llo];
        S2[st][pg] = sAB[64 + st * 32 + pg * 16 + llo];
      }

    #define LDT(o) (*reinterpret_cast<const uint4*>(tile + (o)))
    char* red = smem + RED_OFF;

    #pragma unroll
    for (int st = 0; st < 2; ++st) {
        f32x4 acc[2][4];
        #pragma unroll
        for (int pg = 0; pg < 2; ++pg)
          #pragma unroll
          for (int ot = 0; ot < 4; ++ot) acc[pg][ot] = (f32x4){0.f, 0.f, 0.f, 0.f};

        #pragma unroll
        for (int pg = 0; pg < 2; ++pg) {
            const int ipx = i0 + pg * 2 + (llo >> 3);
            const int jpx = j0 + st * 8 + (llo & 7);

            // -- geometry: L-half addresses + weights (H = +64 immediate) --
            unsigned A[4], B[2];
            float    AG[4], BG[2];
            if (w == 0) {
                geoW<-1,-1,-1, 0>(S1[st][pg], S2[st][pg], ipx, iorg, jpx, jorg, g16, A, AG, B, BG);
            } else if (w == 1) {
                geoW<-1, 1, 0,-1>(S1[st][pg], S2[st][pg], ipx, iorg, jpx, jorg, g16, A, AG, B, BG);
            } else if (w == 2) {
                geoW< 1,-1, 1, 0>(S1[st][pg], S2[st][pg], ipx, iorg, jpx, jorg, g16, A, AG, B, BG);
            } else {
                geoW< 1, 1, 0, 1>(S1[st][pg], S2[st][pg], ipx, iorg, jpx, jorg, g16, A, AG, B, BG);
            }
            unsigned cAddr = pixb(ipx - iorg, jpx - jorg, g16) + (cs ? 64u : 0u);

            // -- hoisted load burst: 13 ds_read_b128 (H-halves via offset:64) --
            uint4 La[4], Ha[4];
            #pragma unroll
            for (int p = 0; p < 4; ++p) {
                La[p] = LDT(A[p]);
                Ha[p] = LDT(A[p] + 64);
            }
            uint4 Lb[2], Hb[2];
            #pragma unroll
            for (int p = 0; p < 2; ++p) {
                Lb[p] = LDT(B[p]);
                Hb[p] = LDT(B[p] + 64);
            }
            bf16x8 bc;
            {
                union { uint4 u; bf16x8 b2; } cv; cv.u = LDT(cAddr); bc = cv.b2;
            }

            // -- consume (same fp element order as r5/r6/r7, packed 2-wide) --
            f32x2 v0[4], v1[4];
            #pragma unroll
            for (int q = 0; q < 4; ++q) { v0[q] = (f32x2){0.f,0.f}; v1[q] = (f32x2){0.f,0.f}; }
            #pragma unroll
            for (int p = 0; p < 4; ++p) fma16p(La[p], Ha[p], AG[p], v0, v1);
            bf16x8 bA0 = packv2(v0), bA1 = packv2(v1);

            f32x2 u0[4], u1[4];
            #pragma unroll
            for (int q = 0; q < 4; ++q) { u0[q] = (f32x2){0.f,0.f}; u1[q] = (f32x2){0.f,0.f}; }
            #pragma unroll
            for (int p = 0; p < 2; ++p) fma16p(Lb[p], Hb[p], BG[p], u0, u1);
            bf16x8 bB0 = packv2(u0), bB1 = packv2(u1);

            #pragma unroll
            for (int ot = 0; ot < 4; ++ot) {
                acc[pg][ot] = __builtin_amdgcn_mfma_f32_16x16x32_bf16(Ata[0][ot], bA0, acc[pg][ot], 0, 0, 0);
                acc[pg][ot] = __builtin_amdgcn_mfma_f32_16x16x32_bf16(Ata[1][ot], bA1, acc[pg][ot], 0, 0, 0);
                acc[pg][ot] = __builtin_amdgcn_mfma_f32_16x16x32_bf16(Atb[0][ot], bB0, acc[pg][ot], 0, 0, 0);
                acc[pg][ot] = __builtin_amdgcn_mfma_f32_16x16x32_bf16(Atb[1][ot], bB1, acc[pg][ot], 0, 0, 0);
            }
            if (w & 1) {
                acc[pg][2] = __builtin_amdgcn_mfma_f32_16x16x32_bf16(Ac0, bc, acc[pg][2], 0, 0, 0);
                acc[pg][3] = __builtin_amdgcn_mfma_f32_16x16x32_bf16(Ac1, bc, acc[pg][3], 0, 0, 0);
            } else {
                acc[pg][0] = __builtin_amdgcn_mfma_f32_16x16x32_bf16(Ac0, bc, acc[pg][0], 0, 0, 0);
                acc[pg][1] = __builtin_amdgcn_mfma_f32_16x16x32_bf16(Ac1, bc, acc[pg][1], 0, 0, 0);
            }
        }

        // ---- cross-wave K-reduce, per-pg rounds in the 20KB side buffer ----
        // (tile region untouched -> stays valid for st=1's tap reads;
        //  same summation order as r4/r6 -> bit-identical)
        #pragma unroll
        for (int pg = 0; pg < 2; ++pg) {
            __syncthreads();     // protect previous round's reads
            #pragma unroll
            for (int ot = 0; ot < 4; ++ot)
                *reinterpret_cast<f32x4*>(red + ((w*64 + lane)*80) + ot*16) = acc[pg][ot];
            __syncthreads();
            const int eq = w;
            f32x4 s = (f32x4){0.f, 0.f, 0.f, 0.f};
            #pragma unroll
            for (int ww = 0; ww < 4; ++ww)
                s += *reinterpret_cast<const f32x4*>(red + ((ww*64 + lane)*80) + eq*16);
            float* ob = out + (size_t)b * COUT * HW
                      + (size_t)(i0 + pg * 2 + (llo >> 3)) * Wn + j0 + st * 8 + (llo & 7);
            #pragma unroll
            for (int r = 0; r < 4; ++r) {
                int o = eq * 16 + g * 4 + r;
                ob[(size_t)o * HW] = s[r] + bias[o];
            }
        }
    }
    #undef LDT
}

// ====================== FALLBACK PATH (round-2, validated) ==================

__device__ __forceinline__ unsigned pk2f(float a, float b) {
    return (unsigned)f2bf(a) | ((unsigned)f2bf(b) << 16);
}

__global__ void prep_weights(const float* __restrict__ weight,
                             unsigned short* __restrict__ Wtb) {
    int e = blockIdx.x * 256 + threadIdx.x;
    if (e >= COUT * KDIM) return;
    int o = e / KDIM, k = e % KDIM;
    int n = k >> 6, c = k & 63;
    int u = n % 3, v = n / 3;
    float w0 = weight[((o * CIN + c) * 3 + 0) * 3 + v];
    float w2 = weight[((o * CIN + c) * 3 + 2) * 3 + v];
    float val = (u == 0) ? w0 : ((u == 1) ? (-w0 - w2) : w2);
    Wtb[o * KDIM + k] = f2bf(val);
}

template<int DX, int DY>
__device__ __forceinline__ void gatherG(const float* __restrict__ xb,
    float s1, float s2, int i, int jj, int klocal,
    char* myrow, unsigned swz, int c0s, int c1s)
{
    int ix0 = 0, ix1 = 0; float wx0 = 1.f, wx1 = 0.f;
    if (DX != 0) {
        float px = (float)DX * s1 + (float)(i + 1);
        float fx = floorf(px);
        float qx0 = fminf(fmaxf(fx, 0.f), 129.f);
        float qx1 = fminf(fmaxf(fx + 1.f, 0.f), 129.f);
        wx0 = 1.f + (qx0 - px); wx1 = 1.f - (qx1 - px);
        ix0 = (int)qx0; ix1 = (int)qx1;
    } else { ix0 = i + 1; }
    int iy0 = 0, iy1 = 0; float wy0 = 1.f, wy1 = 0.f;
    if (DY != 0) {
        float py = (float)DY * s2 + (float)(jj + 1);
        float fy = floorf(py);
        float qy0 = fminf(fmaxf(fy, 0.f), 129.f);
        float qy1 = fminf(fmaxf(fy + 1.f, 0.f), 129.f);
        wy0 = 1.f + (qy0 - py); wy1 = 1.f - (qy1 - py);
        iy0 = (int)qy0; iy1 = (int)qy1;
    } else { iy0 = jj + 1; }

    constexpr int NX = (DX ? 2 : 1), NY = (DY ? 2 : 1), NT = NX * NY;
    unsigned idx[NT]; float g[NT];
    const int   ixs[2] = { ix0, ix1 };  const float wxs[2] = { wx0, wx1 };
    const int   iys[2] = { iy0, iy1 };  const float wys[2] = { wy0, wy1 };
    #pragma unroll
    for (int xi = 0; xi < NX; ++xi)
      #pragma unroll
      for (int yi = 0; yi < NY; ++yi) {
        int ix = ixs[xi], iy = iys[yi];
        bool ok = (ix >= 1) && (ix <= Hn) && (iy >= 1) && (iy <= Wn);
        int cx = min(max(ix, 1), Hn) - 1;
        int cy = min(max(iy, 1), Wn) - 1;
        idx[xi * NY + yi] = (unsigned)(cx * Wn + cy);
        g[xi * NY + yi]   = ok ? wxs[xi] * wys[yi] : 0.f;
      }
    for (int c0 = c0s; c0 < c1s; c0 += 8) {
        float v[8];
        #pragma unroll
        for (int cc = 0; cc < 8; ++cc) {
            unsigned coff = (unsigned)(c0 + cc) * HW;
            float acc2 = 0.f;
            #pragma unroll
            for (int tp = 0; tp < NT; ++tp)
                acc2 = fmaf(g[tp], xb[coff + idx[tp]], acc2);
            v[cc] = acc2;
        }
        uint4 d;
        d.x = pk2f(v[0], v[1]); d.y = pk2f(v[2], v[3]);
        d.z = pk2f(v[4], v[5]); d.w = pk2f(v[6], v[7]);
        unsigned addr = (unsigned)(klocal + c0) * 2u;
        *reinterpret_cast<uint4*>(myrow + (addr ^ swz)) = d;
    }
}

template<int KS>
__device__ __forceinline__ void mfma_phase(const char* emap,
    const unsigned short* __restrict__ Wtb,
    int w, int lane, int passbyte, f32x4 acc[4])
{
    const int llo = lane & 15, lhi = lane >> 4;
    const unsigned prow = (unsigned)(w * 16 + llo);
    const unsigned psw  = (prow & 7u) << 4;
    const char* erow = emap + prow * EROW;
    const char* wtb  = (const char*)Wtb + passbyte + lhi * 16;
    #pragma unroll
    for (int s = 0; s < KS; ++s) {
        unsigned kb = (unsigned)(s * 64 + lhi * 16);
        bf16x8 bf = *reinterpret_cast<const bf16x8*>(erow + (kb ^ psw));
        #pragma unroll
        for (int ot = 0; ot < 4; ++ot) {
            const char* ap = wtb + (ot * 16 + llo) * WROW + s * 64;
            bf16x8 af = *reinterpret_cast<const bf16x8*>(ap);
            acc[ot] = __builtin_amdgcn_mfma_f32_16x16x32_bf16(af, bf, acc[ot], 0, 0, 0);
        }
    }
}

__global__ __launch_bounds__(256, 3) void ddconv_mfma(
    const float* __restrict__ x, const float* __restrict__ alpha,
    const unsigned short* __restrict__ Wtb, const float* __restrict__ bias,
    float* __restrict__ out)
{
    __shared__ __align__(16) char emap[64 * EROW];
    const int blk  = blockIdx.x;
    const int b    = blk >> 8;
    const int rem  = blk & 255;
    const int i    = rem >> 1;
    const int j0   = (rem & 1) << 6;
    const int t    = threadIdx.x;
    const int lane = t & 63;
    const int w    = t >> 6;
    const int jj   = j0 + lane;
    const float* xb = x + (size_t)b * CIN * HW;
    float a = alpha[(b * Hn + i) * Wn + jj];
    float sa, ca;
    sincosf(a, &sa, &ca);
    const float s1 = ca + sa, s2 = ca - sa;
    char* myrow = emap + lane * EROW;
    const unsigned swz = (unsigned)((lane & 7) << 4);
    f32x4 acc[4];
    #pragma unroll
    for (int ot = 0; ot < 4; ++ot) acc[ot] = (f32x4){0.f, 0.f, 0.f, 0.f};
    if (w == 0)      { gatherG<-1,-1>(xb, s1, s2, i, jj,   0, myrow, swz,  0, 48); }
    else if (w == 1) { gatherG<-1,-1>(xb, s1, s2, i, jj,   0, myrow, swz, 48, 64);
                       gatherG<-1, 0>(xb, s1, s2, i, jj,  64, myrow, swz,  0, 64); }
    else if (w == 2) { gatherG<-1, 1>(xb, s1, s2, i, jj, 128, myrow, swz,  0, 48); }
    else             { gatherG<-1, 1>(xb, s1, s2, i, jj, 128, myrow, swz, 48, 64);
                       gatherG< 0,-1>(xb, s1, s2, i, jj, 192, myrow, swz,  0, 64); }
    __syncthreads();
    mfma_phase<8>(emap, Wtb, w, lane, 0, acc);
    __syncthreads();
    if (w == 0)      { gatherG< 1,-1>(xb, s1, s2, i, jj, 128, myrow, swz,  0, 56); }
    else if (w == 1) { gatherG< 1,-1>(xb, s1, s2, i, jj, 128, myrow, swz, 56, 64);
                       gatherG< 1, 1>(xb, s1, s2, i, jj, 256, myrow, swz,  0, 48); }
    else if (w == 2) { gatherG< 1, 1>(xb, s1, s2, i, jj, 256, myrow, swz, 48, 64);
                       gatherG< 0, 1>(xb, s1, s2, i, jj,  64, myrow, swz,  0, 64); }
    else             { gatherG< 1, 0>(xb, s1, s2, i, jj, 192, myrow, swz,  0, 64);
                       gatherG< 0, 0>(xb, s1, s2, i, jj,   0, myrow, swz,  0, 64); }
    __syncthreads();
    mfma_phase<10>(emap, Wtb, w, lane, 512, acc);
    const int llo = lane & 15, lhi = lane >> 4;
    float* ob = out + (size_t)b * COUT * HW + (size_t)i * Wn + j0 + w * 16 + llo;
    #pragma unroll
    for (int ot = 0; ot < 4; ++ot)
      #pragma unroll
      for (int r = 0; r < 4; ++r) {
        int o = ot * 16 + lhi * 4 + r;
        ob[(size_t)o * HW] = acc[ot][r] + bias[o];
      }
}

// ============================================================================

extern "C" void kernel_launch(void* const* d_in, const int* in_sizes, int n_in,
                              void* d_out, int out_size, void* d_ws, size_t ws_size,
                              hipStream_t stream) {
    const float* x      = (const float*)d_in[0];
    const float* alpha  = (const float*)d_in[1];
    const float* weight = (const float*)d_in[2];
    const float* bias   = (const float*)d_in[3];
    float* out = (float*)d_out;

    const size_t WT_BYTES = (size_t)COUT * KDIM * 2;          // 73728
    const size_t XT_BYTES = (size_t)4 * HW * CIN * 2;         // 8388608

    if (ws_size >= WT_BYTES + XT_BYTES) {
        unsigned short* Wtb2 = (unsigned short*)d_ws;
        unsigned short* xt   = (unsigned short*)((char*)d_ws + WT_BYTES);
        prep_fused<<<1168, 256, 0, stream>>>(x, weight, xt, Wtb2);
        ddconv_ws3<<<4 * (Hn / 4) * (Wn / 16), 256, 0, stream>>>(xt, alpha, Wtb2, bias, out);
    } else {
        unsigned short* Wtb = (unsigned short*)d_ws;          // round-2 layout
        prep_weights<<<(COUT * KDIM + 255) / 256, 256, 0, stream>>>(weight, Wtb);
        ddconv_mfma<<<4 * Hn * (Wn / 64), 256, 0, stream>>>(x, alpha, Wtb, bias, out);
    }
}